// Round 4
// baseline (66.817 us; speedup 1.0000x reference)
//
#include <hip/hip_runtime.h>
#include <math.h>

// OrthogonalButterfly: X (1024 x 8192) fp32, 20 butterfly layers, stride 2^(l%10).
// Register-resident: thread owns 32 rows of one column; 3 LDS ownership
// transposes (A: 32 consecutive rows -> strides 1..16 local; B: rows mod 32 ->
// strides 32..512 local). Angle table precomputed (cos,sin) in d_ws, permuted
// so each thread reads 128B contiguous per layer.
// R2: block = 1024 thr x 32 cols (full 128B line per row), grid 256, LDS 128KB.
// R3: streamed table loads (no effect -- scheduler re-hoisted into the same
//     pressure; VGPR stuck at 64, dur stuck at 53us across 3 geometries).
// R4: (a) amdgpu_waves_per_eu(4,4): LDS caps us at 4 waves/EU anyway, so let
//     the allocator use the real budget (~512 VGPR) instead of 64.
//     (b) explicit 1-layer-deep double-buffered table prefetch (q/qn float4[8])
//     so each layer's 8 table loads are issued under the previous layer's FMAs.

#define NROW   1024
#define BATCH  8192
#define DEPTH  20
#define NANG   512
#define TAB_ELEMS (DEPTH * NANG)
#define TAB_BYTES ((size_t)TAB_ELEMS * 8)

// ---------------- angle table build ----------------
// table slot mapping per layer l (sp = l % 10):
//   A-layers (sp<=4, s=2^sp):  slot = a  (identity)
//   B-layers (sp>=5, sigma=2^(sp-5)): slot = g*16 + p, p = K*sigma + m,
//        a = K*32*sigma + 32*m + g
__global__ void build_tab_kernel(const float* __restrict__ ang,
                                 float2* __restrict__ tab) {
    int idx = blockIdx.x * blockDim.x + threadIdx.x;
    if (idx >= TAB_ELEMS) return;
    int l = idx >> 9;
    int slot = idx & (NANG - 1);
    int sp = l % 10;
    int a;
    if (sp <= 4) {
        a = slot;
    } else {
        int g = slot >> 4;
        int p = slot & 15;
        int sgp = sp - 5;                 // log2(sigma)
        int K = p >> sgp;
        int m = p & ((1 << sgp) - 1);
        a = (K << (5 + sgp)) | (m << 5) | g;
    }
    float th = ang[l * NANG + a];
    float sv, cv;
    sincosf(th, &sv, &cv);
    tab[idx] = make_float2(cv, sv);
}

// ---------------- main kernel ----------------
__device__ __forceinline__ void rot(float& a, float& b, float cv, float sv) {
    float x0 = a, x1 = b;
    a = cv * x0 + sv * x1;
    b = cv * x1 - sv * x0;
}

// Apply one layer from q[8] (16 cos/sin pairs packed x,y|z,w), compile-time S.
template<int S>
__device__ __forceinline__ void apply_layer(float y[32], const float4 q[8]) {
    #pragma unroll
    for (int u = 0; u < 8; ++u) {
        {
            int p = 2 * u;
            int i0 = 2 * (p / S) * S + (p % S);   // constant-folds
            rot(y[i0], y[i0 + S], q[u].x, q[u].y);
        }
        {
            int p = 2 * u + 1;
            int i0 = 2 * (p / S) * S + (p % S);
            rot(y[i0], y[i0 + S], q[u].z, q[u].w);
        }
    }
}

__device__ __forceinline__ void pref8(float4 q[8], const float4* __restrict__ s) {
    #pragma unroll
    for (int u = 0; u < 8; ++u) q[u] = s[u];
}

__device__ __forceinline__ void cp8(float4 d[8], const float4 s[8]) {
    #pragma unroll
    for (int u = 0; u < 8; ++u) d[u] = s[u];
}

// 5 layers (S = 1,2,4,8,16) with 1-deep table prefetch. q holds layer lbase's
// slice on entry; on exit q holds the slice at `nxt` (prefetched under the
// S=16 layer's FMAs) if PRE, else undefined.
template<bool PRE>
__device__ __forceinline__ void group5_tab(float y[32], float4 q[8],
                                           const float2* __restrict__ tab,
                                           int lbase,
                                           const float2* __restrict__ nxt,
                                           int sub) {
    const float4* s1 = reinterpret_cast<const float4*>(tab + (lbase + 1) * NANG + 16 * sub);
    const float4* s2 = reinterpret_cast<const float4*>(tab + (lbase + 2) * NANG + 16 * sub);
    const float4* s3 = reinterpret_cast<const float4*>(tab + (lbase + 3) * NANG + 16 * sub);
    const float4* s4 = reinterpret_cast<const float4*>(tab + (lbase + 4) * NANG + 16 * sub);
    float4 qn[8];
    pref8(qn, s1); apply_layer<1 >(y, q); cp8(q, qn);
    pref8(qn, s2); apply_layer<2 >(y, q); cp8(q, qn);
    pref8(qn, s3); apply_layer<4 >(y, q); cp8(q, qn);
    pref8(qn, s4); apply_layer<8 >(y, q); cp8(q, qn);
    if (PRE) {
        const float4* s5 = reinterpret_cast<const float4*>(nxt + 16 * sub);
        pref8(qn, s5); apply_layer<16>(y, q); cp8(q, qn);
    } else {
        apply_layer<16>(y, q);
    }
}

// ---- fallback (no workspace): compute sincos inline ----
template<int S, bool PB>
__device__ __forceinline__ void layer_notab(float y[32],
                                            const float* __restrict__ angL,
                                            int sub) {
    #pragma unroll
    for (int p = 0; p < 16; ++p) {
        int a;
        if (PB) {
            int K = p / S, m = p % S;          // S = sigma (compile-time)
            a = K * 32 * S + 32 * m + sub;
        } else {
            a = 16 * sub + p;
        }
        float th = angL[a];
        float sv, cv;
        __sincosf(th, &sv, &cv);
        int i0 = 2 * (p / S) * S + (p % S);
        rot(y[i0], y[i0 + S], cv, sv);
    }
}

template<bool PB>
__device__ __forceinline__ void group5_notab(float y[32], const float* ang,
                                             int lbase, int sub) {
    layer_notab<1,  PB>(y, ang + (lbase + 0) * NANG, sub);
    layer_notab<2,  PB>(y, ang + (lbase + 1) * NANG, sub);
    layer_notab<4,  PB>(y, ang + (lbase + 2) * NANG, sub);
    layer_notab<8,  PB>(y, ang + (lbase + 3) * NANG, sub);
    layer_notab<16, PB>(y, ang + (lbase + 4) * NANG, sub);
}

// LDS address for element (col c, row r):
//   c*1024 + (r XOR ((((r>>5) ^ c) & 7) << 2))
// b128 writes: quad-group = u ^ ((sub^c)&7) -> balanced (8 lanes/quad over a
// wave = minimum for 16B/lane). b32 strided accesses: ~4-way, known ~4us tax.
__device__ __forceinline__ void t_a2b(float y[32], float* lds, int c, int sub) {
    __syncthreads();
    {
        int xr = ((sub ^ c) & 7) << 2;
        float* base = lds + c * 1024 + 32 * sub;
        #pragma unroll
        for (int u = 0; u < 8; ++u) {
            *reinterpret_cast<float4*>(base + ((4 * u) ^ xr)) =
                make_float4(y[4 * u], y[4 * u + 1], y[4 * u + 2], y[4 * u + 3]);
        }
    }
    __syncthreads();
    #pragma unroll
    for (int k = 0; k < 32; ++k)
        y[k] = lds[c * 1024 + 32 * k + (sub ^ ((((k ^ c) & 7)) << 2))];
}

__device__ __forceinline__ void t_b2a(float y[32], float* lds, int c, int sub) {
    __syncthreads();
    #pragma unroll
    for (int k = 0; k < 32; ++k)
        lds[c * 1024 + 32 * k + (sub ^ ((((k ^ c) & 7)) << 2))] = y[k];
    __syncthreads();
    {
        int xr = ((sub ^ c) & 7) << 2;
        const float* base = lds + c * 1024 + 32 * sub;
        #pragma unroll
        for (int u = 0; u < 8; ++u) {
            float4 v = *reinterpret_cast<const float4*>(base + ((4 * u) ^ xr));
            y[4 * u]     = v.x;
            y[4 * u + 1] = v.y;
            y[4 * u + 2] = v.z;
            y[4 * u + 3] = v.w;
        }
    }
}

template<bool USE_TAB>
__global__ __launch_bounds__(1024)
__attribute__((amdgpu_waves_per_eu(4, 4)))
void butterfly_kernel(
        const float* __restrict__ X, const float* __restrict__ ang,
        const float2* __restrict__ tab, float* __restrict__ out) {
    __shared__ float lds[32 * 1024];    // 128 KB -> 1 block/CU, 16 waves
    int t = threadIdx.x;
    int c = t & 31;                     // 32 cols = one full 128B line
    int sub = t >> 5;                   // [0,32)
    int col = (blockIdx.x << 5) + c;

    float y[32];
    float4 q[8];
    if (USE_TAB)                        // issue table prefetch before X loads
        pref8(q, reinterpret_cast<const float4*>(tab + 16 * sub));

    const float* Xp = X + col;
    #pragma unroll
    for (int i = 0; i < 32; ++i)
        y[i] = Xp[(32 * sub + i) * BATCH];       // phase A: row = 32*sub + i

    if (USE_TAB) {
        group5_tab<true >(y, q, tab, 0,  tab + 5 * NANG, sub);   // s=1..16
        t_a2b(y, lds, c, sub);                                   // -> phase B
        group5_tab<true >(y, q, tab, 5,  tab + 10 * NANG, sub);  // s=32..512
        t_b2a(y, lds, c, sub);                                   // -> phase A
        group5_tab<true >(y, q, tab, 10, tab + 15 * NANG, sub);  // s=1..16
        t_a2b(y, lds, c, sub);                                   // -> phase B
        group5_tab<false>(y, q, tab, 15, nullptr, sub);          // s=32..512
    } else {
        group5_notab<false>(y, ang, 0, sub);
        t_a2b(y, lds, c, sub);
        group5_notab<true >(y, ang, 5, sub);
        t_b2a(y, lds, c, sub);
        group5_notab<false>(y, ang, 10, sub);
        t_a2b(y, lds, c, sub);
        group5_notab<true >(y, ang, 15, sub);
    }

    float* Op = out + col;
    #pragma unroll
    for (int k = 0; k < 32; ++k)
        Op[(sub + 32 * k) * BATCH] = y[k];         // phase B layout store
}

extern "C" void kernel_launch(void* const* d_in, const int* in_sizes, int n_in,
                              void* d_out, int out_size, void* d_ws, size_t ws_size,
                              hipStream_t stream) {
    (void)in_sizes; (void)n_in; (void)out_size;
    const float* X   = (const float*)d_in[0];
    const float* ang = (const float*)d_in[1];
    float* out = (float*)d_out;

    bool use_tab = (d_ws != nullptr) && (ws_size >= TAB_BYTES);
    if (use_tab) {
        float2* tab = (float2*)d_ws;
        build_tab_kernel<<<(TAB_ELEMS + 255) / 256, 256, 0, stream>>>(ang, tab);
        butterfly_kernel<true><<<256, 1024, 0, stream>>>(X, ang, tab, out);
    } else {
        butterfly_kernel<false><<<256, 1024, 0, stream>>>(X, ang, nullptr, out);
    }
}

// Round 5
// 43.186 us; speedup vs baseline: 1.5472x; 1.5472x over previous
//
#include <hip/hip_runtime.h>
#include <math.h>

// OrthogonalButterfly: X (1024 x 8192) fp32, 20 butterfly layers, stride 2^(l%10).
// R1-R4 lesson: allocator pins VGPR=64 no matter what; y[32] designs spill
// ~36 dwords/thread (constant +36MB HBM writes, 53us floor; R4's deeper
// prefetch doubled FETCH+WRITE = scratch traffic confirmed).
// R5: y[16] per thread so 64 VGPR suffices. 1024 thr = 64 subs x 16 cols,
// grid 512, LDS 64KB -> 2 blocks/CU, 32 waves/CU. Three ownership phases:
//   A: row bits {0..3}  (strides 1,2,4,8)
//   C: row bits {4..7}  (strides 16,32,64,128)
//   B: row bits {8,9,0,1} (strides 256,512)
// Schedule: load(A) 4L T 4L T 2L T 4L T 4L T 2L store(B) -- 5 LDS transposes.
// Swizzle r ^ ((c&3)<<2) ^ ((c>>2&1)<<4): all b128 8-lanes/quad (min),
// all b32 2-lanes/bank (free).

#define NROW   1024
#define BATCH  8192
#define DEPTH  20
#define NANG   512
#define TAB_ELEMS (DEPTH * NANG)
#define TAB_BYTES ((size_t)TAB_ELEMS * 8)

// ---------------- angle table build ----------------
// slot = 8*sub + p (sub in [0,64), p in [0,8)); angle index a per phase:
//   A (sp 0-3):  a = slot
//   C (sp 4-7):  a = (sub>>4)*128 + p*16 + (sub&15)
//   B (sp 8-9):  a = (p>>2)*256 + sub*4 + (p&3)
__global__ void build_tab_kernel(const float* __restrict__ ang,
                                 float2* __restrict__ tab) {
    int idx = blockIdx.x * blockDim.x + threadIdx.x;
    if (idx >= TAB_ELEMS) return;
    int l = idx >> 9;
    int slot = idx & (NANG - 1);
    int sp = l % 10;
    int sub = slot >> 3, p = slot & 7;
    int a;
    if (sp <= 3)       a = slot;
    else if (sp <= 7)  a = (sub >> 4) * 128 + p * 16 + (sub & 15);
    else               a = ((p >> 2) << 8) | (sub << 2) | (p & 3);
    float th = ang[l * NANG + a];
    float sv, cv;
    sincosf(th, &sv, &cv);
    tab[idx] = make_float2(cv, sv);
}

// ---------------- main kernel ----------------
__device__ __forceinline__ void rot(float& a, float& b, float cv, float sv) {
    float x0 = a, x1 = b;
    a = cv * x0 + sv * x1;
    b = cv * x1 - sv * x0;
}

// One layer on 16 register rows, local pair-stride SL (1,2,4,8).
// Pairs p in [0,8): i0 = 2*(p/SL)*SL + p%SL, partner i0+SL. Table slice is
// 4 float4 at tl + 8*sub (same address for the 16 c-lanes -> broadcast).
template<int SL>
__device__ __forceinline__ void layer_tab(float y[16],
                                          const float2* __restrict__ tl,
                                          int sub) {
    const float4* q4 = reinterpret_cast<const float4*>(tl + 8 * sub);
    #pragma unroll
    for (int v = 0; v < 4; ++v) {
        float4 q = q4[v];
        int p0 = 2 * v, p1 = 2 * v + 1;
        int a0 = 2 * (p0 / SL) * SL + p0 % SL;   // constant-folds
        int a1 = 2 * (p1 / SL) * SL + p1 % SL;
        rot(y[a0], y[a0 + SL], q.x, q.y);
        rot(y[a1], y[a1 + SL], q.z, q.w);
    }
}

// Fallback without workspace table: inline sincos, per-phase angle index.
template<int SL, int PH>   // PH: 0=A, 1=C, 2=B
__device__ __forceinline__ void layer_notab(float y[16],
                                            const float* __restrict__ angL,
                                            int sub) {
    #pragma unroll
    for (int p = 0; p < 8; ++p) {
        int a;
        if (PH == 0)      a = 8 * sub + p;
        else if (PH == 1) a = (sub >> 4) * 128 + p * 16 + (sub & 15);
        else              a = ((p >> 2) << 8) | (sub << 2) | (p & 3);
        float th = angL[a];
        float sv, cv;
        __sincosf(th, &sv, &cv);
        int i0 = 2 * (p / SL) * SL + p % SL;
        rot(y[i0], y[i0 + SL], cv, sv);
    }
}

// LDS word address for (col c, row r), 16 cols x 1024 rows = 64KB.
__device__ __forceinline__ int swz(int c, int r) {
    return (c << 10) + (r ^ ((c & 3) << 2) ^ (((c >> 2) & 1) << 4));
}

// Row sets per phase:
//   A: r = 16*sub + i              (i 0..15)
//   C: r = (sub>>4)*256 + i*16 + (sub&15)
//   B: r = (i>>2)*256 + sub*4 + (i&3)
__device__ __forceinline__ void wrA(const float y[16], float* lds, int c, int sub) {
    #pragma unroll
    for (int u = 0; u < 4; ++u)
        *reinterpret_cast<float4*>(&lds[swz(c, 16 * sub + 4 * u)]) =
            make_float4(y[4*u], y[4*u+1], y[4*u+2], y[4*u+3]);
}
__device__ __forceinline__ void rdA(float y[16], const float* lds, int c, int sub) {
    #pragma unroll
    for (int u = 0; u < 4; ++u) {
        float4 v = *reinterpret_cast<const float4*>(&lds[swz(c, 16 * sub + 4 * u)]);
        y[4*u] = v.x; y[4*u+1] = v.y; y[4*u+2] = v.z; y[4*u+3] = v.w;
    }
}
__device__ __forceinline__ void wrC(const float y[16], float* lds, int c, int sub) {
    int base = (sub >> 4) * 256 + (sub & 15);
    #pragma unroll
    for (int i = 0; i < 16; ++i)
        lds[swz(c, base + i * 16)] = y[i];
}
__device__ __forceinline__ void rdC(float y[16], const float* lds, int c, int sub) {
    int base = (sub >> 4) * 256 + (sub & 15);
    #pragma unroll
    for (int i = 0; i < 16; ++i)
        y[i] = lds[swz(c, base + i * 16)];
}
__device__ __forceinline__ void wrB(const float y[16], float* lds, int c, int sub) {
    #pragma unroll
    for (int ib = 0; ib < 4; ++ib)
        *reinterpret_cast<float4*>(&lds[swz(c, ib * 256 + sub * 4)]) =
            make_float4(y[4*ib], y[4*ib+1], y[4*ib+2], y[4*ib+3]);
}
__device__ __forceinline__ void rdB(float y[16], const float* lds, int c, int sub) {
    #pragma unroll
    for (int ib = 0; ib < 4; ++ib) {
        float4 v = *reinterpret_cast<const float4*>(&lds[swz(c, ib * 256 + sub * 4)]);
        y[4*ib] = v.x; y[4*ib+1] = v.y; y[4*ib+2] = v.z; y[4*ib+3] = v.w;
    }
}

template<bool USE_TAB>
__global__ __launch_bounds__(1024) void butterfly_kernel(
        const float* __restrict__ X, const float* __restrict__ ang,
        const float2* __restrict__ tab, float* __restrict__ out) {
    __shared__ float lds[16 * 1024];     // 64 KB -> 2 blocks/CU, 32 waves/CU
    int t = threadIdx.x;
    int c = t & 15;
    int sub = t >> 4;                    // [0,64)
    int bid = blockIdx.x;
    int L = ((bid & 7) << 6) | (bid >> 3);   // XCD-aware, bijective (512 = 8*64)
    int col = (L << 4) + c;

    float y[16];
    const float* Xp = X + col;
    #pragma unroll
    for (int i = 0; i < 16; ++i)
        y[i] = Xp[(16 * sub + i) * BATCH];       // phase A layout

    if (USE_TAB) {
        layer_tab<1>(y, tab +  0 * NANG, sub);   // s=1
        layer_tab<2>(y, tab +  1 * NANG, sub);   // s=2
        layer_tab<4>(y, tab +  2 * NANG, sub);   // s=4
        layer_tab<8>(y, tab +  3 * NANG, sub);   // s=8
        wrA(y, lds, c, sub); __syncthreads(); rdC(y, lds, c, sub);
        layer_tab<1>(y, tab +  4 * NANG, sub);   // s=16
        layer_tab<2>(y, tab +  5 * NANG, sub);   // s=32
        layer_tab<4>(y, tab +  6 * NANG, sub);   // s=64
        layer_tab<8>(y, tab +  7 * NANG, sub);   // s=128
        __syncthreads(); wrC(y, lds, c, sub); __syncthreads(); rdB(y, lds, c, sub);
        layer_tab<4>(y, tab +  8 * NANG, sub);   // s=256
        layer_tab<8>(y, tab +  9 * NANG, sub);   // s=512
        __syncthreads(); wrB(y, lds, c, sub); __syncthreads(); rdA(y, lds, c, sub);
        layer_tab<1>(y, tab + 10 * NANG, sub);
        layer_tab<2>(y, tab + 11 * NANG, sub);
        layer_tab<4>(y, tab + 12 * NANG, sub);
        layer_tab<8>(y, tab + 13 * NANG, sub);
        __syncthreads(); wrA(y, lds, c, sub); __syncthreads(); rdC(y, lds, c, sub);
        layer_tab<1>(y, tab + 14 * NANG, sub);
        layer_tab<2>(y, tab + 15 * NANG, sub);
        layer_tab<4>(y, tab + 16 * NANG, sub);
        layer_tab<8>(y, tab + 17 * NANG, sub);
        __syncthreads(); wrC(y, lds, c, sub); __syncthreads(); rdB(y, lds, c, sub);
        layer_tab<4>(y, tab + 18 * NANG, sub);
        layer_tab<8>(y, tab + 19 * NANG, sub);
    } else {
        layer_notab<1,0>(y, ang +  0 * NANG, sub);
        layer_notab<2,0>(y, ang +  1 * NANG, sub);
        layer_notab<4,0>(y, ang +  2 * NANG, sub);
        layer_notab<8,0>(y, ang +  3 * NANG, sub);
        wrA(y, lds, c, sub); __syncthreads(); rdC(y, lds, c, sub);
        layer_notab<1,1>(y, ang +  4 * NANG, sub);
        layer_notab<2,1>(y, ang +  5 * NANG, sub);
        layer_notab<4,1>(y, ang +  6 * NANG, sub);
        layer_notab<8,1>(y, ang +  7 * NANG, sub);
        __syncthreads(); wrC(y, lds, c, sub); __syncthreads(); rdB(y, lds, c, sub);
        layer_notab<4,2>(y, ang +  8 * NANG, sub);
        layer_notab<8,2>(y, ang +  9 * NANG, sub);
        __syncthreads(); wrB(y, lds, c, sub); __syncthreads(); rdA(y, lds, c, sub);
        layer_notab<1,0>(y, ang + 10 * NANG, sub);
        layer_notab<2,0>(y, ang + 11 * NANG, sub);
        layer_notab<4,0>(y, ang + 12 * NANG, sub);
        layer_notab<8,0>(y, ang + 13 * NANG, sub);
        __syncthreads(); wrA(y, lds, c, sub); __syncthreads(); rdC(y, lds, c, sub);
        layer_notab<1,1>(y, ang + 14 * NANG, sub);
        layer_notab<2,1>(y, ang + 15 * NANG, sub);
        layer_notab<4,1>(y, ang + 16 * NANG, sub);
        layer_notab<8,1>(y, ang + 17 * NANG, sub);
        __syncthreads(); wrC(y, lds, c, sub); __syncthreads(); rdB(y, lds, c, sub);
        layer_notab<4,2>(y, ang + 18 * NANG, sub);
        layer_notab<8,2>(y, ang + 19 * NANG, sub);
    }

    // store in phase-B layout: r = (i>>2)*256 + sub*4 + (i&3)
    float* Op = out + col;
    #pragma unroll
    for (int i = 0; i < 16; ++i)
        Op[(((i >> 2) << 8) | (sub << 2) | (i & 3)) * BATCH] = y[i];
}

extern "C" void kernel_launch(void* const* d_in, const int* in_sizes, int n_in,
                              void* d_out, int out_size, void* d_ws, size_t ws_size,
                              hipStream_t stream) {
    (void)in_sizes; (void)n_in; (void)out_size;
    const float* X   = (const float*)d_in[0];
    const float* ang = (const float*)d_in[1];
    float* out = (float*)d_out;

    bool use_tab = (d_ws != nullptr) && (ws_size >= TAB_BYTES);
    if (use_tab) {
        float2* tab = (float2*)d_ws;
        build_tab_kernel<<<(TAB_ELEMS + 255) / 256, 256, 0, stream>>>(ang, tab);
        butterfly_kernel<true><<<512, 1024, 0, stream>>>(X, ang, tab, out);
    } else {
        butterfly_kernel<false><<<512, 1024, 0, stream>>>(X, ang, nullptr, out);
    }
}